// Round 8
// baseline (382.345 us; speedup 1.0000x reference)
//
#include <hip/hip_runtime.h>
#include <hip/hip_bf16.h>
#include <stdint.h>

#define M_TOT 16384
#define K_TOT 4096
#define N_COLS 4096
#define NS 409
#define NP 448            // padded W rows: 4 waves x 7 frags x 16
#define NT 128            // K-steps of 32

typedef __attribute__((ext_vector_type(4))) float f32x4;
typedef __attribute__((ext_vector_type(8))) short bf16x8;

__device__ inline bf16x8 pack8(f32x4 lo, f32x4 hi) {
  union { __hip_bfloat16 h[8]; bf16x8 v; } r;
  r.h[0] = __float2bfloat16(lo[0]); r.h[1] = __float2bfloat16(lo[1]);
  r.h[2] = __float2bfloat16(lo[2]); r.h[3] = __float2bfloat16(lo[3]);
  r.h[4] = __float2bfloat16(hi[0]); r.h[5] = __float2bfloat16(hi[1]);
  r.h[6] = __float2bfloat16(hi[2]); r.h[7] = __float2bfloat16(hi[3]);
  return r.v;
}

// W fp32 [409][4096] -> bf16 [448][4096] in ws, zero rows 409..447
__global__ __launch_bounds__(256) void convert_w(const float* __restrict__ Wf,
                                                 __hip_bfloat16* __restrict__ Wb) {
  const int gt = blockIdx.x * 256 + threadIdx.x;   // 229376 threads
  const int row = gt >> 9;                         // 512 threads per row
  const int c8 = (gt & 511) << 3;
  bf16x8 o = {};
  if (row < NS)
    o = pack8(*(const f32x4*)(Wf + (size_t)row * K_TOT + c8),
              *(const f32x4*)(Wf + (size_t)row * K_TOT + c8 + 4));
  *(bf16x8*)(Wb + (size_t)row * K_TOT + c8) = o;
}

// Streaming GEMM, no LDS / no barriers in the K-loop.
// 256 blocks x 256 threads (4 waves). Block owns 64 rows x all 448 cols.
// Wave tile 64x112 (mrep=4, nrep=7): B-frags from L2 (W-bf16 hot, read once
// per block), A-frags direct from global (all 4 waves share the same 8KB/step
// window -> L1 hits), cvt to bf16 in-reg. Fused scatter epilogue via LDS.
template <bool PRECONV>
__global__ __launch_bounds__(256, 1) void gemm_stream(
    const float* __restrict__ X, const float* __restrict__ Wf,
    const __hip_bfloat16* __restrict__ Wb, const int* __restrict__ idx,
    float* __restrict__ OUT) {
  extern __shared__ float rowbuf[];   // 4 rows x 4096 f32 = 64 KB
  const int tid = threadIdx.x;
  const int lane = tid & 63;
  const int wv = tid >> 6;    // 0..3 : column quarter (112 cols)
  const int l16 = lane & 15;
  const int kg = lane >> 4;   // 0..3
  const int row0 = blockIdx.x * 64;

  int cidx[7];
#pragma unroll
  for (int j = 0; j < 7; ++j) {
    const int n = wv * 112 + j * 16 + l16;
    cidx[j] = (n < NS) ? idx[n] : -1;
  }

  f32x4 acc[4][7] = {};

  const float* abase = X + (size_t)(row0 + l16) * K_TOT + kg * 8;

#pragma unroll 1
  for (int t = 0; t < NT; ++t) {
    const int ko = t * 32;
    // B fragments: 7 x 16B direct from L2-resident W-bf16
    bf16x8 bfr[7];
    if (PRECONV) {
#pragma unroll
      for (int j = 0; j < 7; ++j) {
        const int n = wv * 112 + j * 16 + l16;
        bfr[j] = *(const bf16x8*)(Wb + (size_t)n * K_TOT + ko + kg * 8);
      }
    } else {
#pragma unroll
      for (int j = 0; j < 7; ++j) {
        const int n = wv * 112 + j * 16 + l16;
        f32x4 lo = {}, hi = {};
        if (n < NS) {
          const float* s = Wf + (size_t)n * K_TOT + ko + kg * 8;
          lo = *(const f32x4*)s;
          hi = *(const f32x4*)(s + 4);
        }
        bfr[j] = pack8(lo, hi);
      }
    }
    // A fragments: 4 x (2 x f32x4) direct from global, cvt in-reg
    bf16x8 af[4];
#pragma unroll
    for (int i = 0; i < 4; ++i) {
      const float* s = abase + (size_t)(i * 16) * K_TOT + ko;
      af[i] = pack8(*(const f32x4*)s, *(const f32x4*)(s + 4));
    }
#pragma unroll
    for (int i = 0; i < 4; ++i)
#pragma unroll
      for (int j = 0; j < 7; ++j)
        acc[i][j] = __builtin_amdgcn_mfma_f32_16x16x32_bf16(af[i], bfr[j],
                                                            acc[i][j], 0, 0, 0);
  }

  // ---- fused epilogue: compose 4 full 4096-col rows per pass, stream out ----
  __syncthreads();
#pragma unroll 1
  for (int p = 0; p < 16; ++p) {
#pragma unroll
    for (int z = 0; z < 16; ++z) {
      f32x4 zv = {};
      *(f32x4*)(rowbuf + z * 1024 + tid * 4) = zv;
    }
    __syncthreads();
    // thread rows: r = i*16 + kg*4 + q ; pass p covers [4p,4p+4): i=p>>2, kg=p&3
    if (kg == (p & 3)) {
      const int i = p >> 2;
#pragma unroll
      for (int q = 0; q < 4; ++q) {
        float* dst = rowbuf + q * N_COLS;
#pragma unroll
        for (int j = 0; j < 7; ++j)
          if (cidx[j] >= 0) dst[cidx[j]] = acc[i][j][q];
      }
    }
    __syncthreads();
    float* ob = OUT + (size_t)(row0 + p * 4) * N_COLS;
#pragma unroll
    for (int z = 0; z < 16; ++z) {
      const int off = z * 1024 + tid * 4;
      *(f32x4*)(ob + off) = *(const f32x4*)(rowbuf + off);
    }
    __syncthreads();
  }
}

extern "C" void kernel_launch(void* const* d_in, const int* in_sizes, int n_in,
                              void* d_out, int out_size, void* d_ws, size_t ws_size,
                              hipStream_t stream) {
  const float* x = (const float*)d_in[0];
  const float* w = (const float*)d_in[2];
  const int* idx = (const int*)d_in[3];
  float* out = (float*)d_out;

  const size_t LDS_SZ = 4 * N_COLS * sizeof(float);  // 65536
  const size_t need = (size_t)NP * K_TOT * 2;        // 3.67 MB bf16 W
  if (ws_size >= need) {
    __hip_bfloat16* wb = (__hip_bfloat16*)d_ws;
    convert_w<<<NP * K_TOT / 8 / 256, 256, 0, stream>>>(w, wb);
    hipFuncSetAttribute(reinterpret_cast<const void*>(&gemm_stream<true>),
                        hipFuncAttributeMaxDynamicSharedMemorySize, LDS_SZ);
    gemm_stream<true><<<M_TOT / 64, 256, LDS_SZ, stream>>>(x, w, wb, idx, out);
  } else {
    hipFuncSetAttribute(reinterpret_cast<const void*>(&gemm_stream<false>),
                        hipFuncAttributeMaxDynamicSharedMemorySize, LDS_SZ);
    gemm_stream<false><<<M_TOT / 64, 256, LDS_SZ, stream>>>(x, w, nullptr, idx, out);
  }
}